// Round 7
// baseline (2244.606 us; speedup 1.0000x reference)
//
#include <hip/hip_runtime.h>

namespace {
constexpr int CH = 640, HW = 25, MS = 125;
constexpr int CHW = CH * HW;    // 16000
constexpr float GAMMA = 20.f, GAMMA2 = 10.f;
constexpr float EPS = 1e-12f;
}

// Shot-mean + L2-normalize (over c) + transpose to sup_t[b][nk][c]. (round-1 verbatim)
__global__ __launch_bounds__(256)
void prep_sup_kernel(const float* __restrict__ sup, float* __restrict__ sup_t) {
  __shared__ __align__(16) float m[CHW];   // mean tile [c][k]
  __shared__ float inv[HW];
  const int bn = blockIdx.x;               // b*5 + n
  const float* base = sup + (size_t)(bn / 5) * (25 * CHW)
                          + (size_t)(bn % 5) * (5 * CHW);
  for (int idx = threadIdx.x; idx < CHW; idx += 256) {
    float s = 0.f;
    #pragma unroll
    for (int sh = 0; sh < 5; ++sh) s += base[sh * CHW + idx];
    m[idx] = s * 0.2f;
  }
  __syncthreads();
  {
    int i = threadIdx.x >> 3, s8 = threadIdx.x & 7;
    if (i < HW) {
      float p = 0.f;
      for (int c = s8; c < CH; c += 8) { float v = m[c * HW + i]; p += v * v; }
      p += __shfl_xor(p, 1); p += __shfl_xor(p, 2); p += __shfl_xor(p, 4);
      if (s8 == 0) inv[i] = rsqrtf(p + EPS);
    }
  }
  __syncthreads();
  float* outp = sup_t + (size_t)bn * CHW;  // [nk][c], coalesced writes
  for (int idx = threadIdx.x; idx < CHW; idx += 256) {
    int k = idx / CH, c = idx - k * CH;
    outp[idx] = m[c * HW + k] * inv[k];
  }
}

// Per-(b,q): chunked-A GEMM -> softmaxes -> reduced 25x25 f64 Katz solve -> outputs.
__global__ __launch_bounds__(256, 4)
void melmask_kernel(const float* __restrict__ qry, const float* __restrict__ sup_t,
                    float* __restrict__ out) {
  __shared__ __align__(16) float smem[9224];
  // [0,3125)     Sld = S[i][nk] (stride 125); later in-place P
  // [3136,5696)  stile 128x20 sup chunk; later ksf[125] overlay
  // [5696,6096)  qtile 16x25 query chunk
  // [6096,9221)  Qm[j][i] (stride 25); later overlaid by Msol (675 f64)
  float* Sld   = smem;
  float* stile = smem + 3136;
  float* qtile = smem + 5696;
  float* Qm    = smem + 6096;
  double* Msol = (double*)(smem + 6096);   // 6096*4 % 8 == 0
  float* ksf   = smem + 3136;
  __shared__ double xsd[HW];
  __shared__ float invq[HW];
  __shared__ float kqs[HW];

  const int tid = threadIdx.x;
  const int bq = blockIdx.x;               // b*75 + q
  const int b = bq / 75;
  const float* qbase = qry + (size_t)bq * CHW;
  const float* sbase = sup_t + (size_t)b * (MS * CH);

  // GEMM: S[i][nk] = sum_c q[c*25+i] * sup_t[nk*640+c]   (25 x 125, K=640)
  const int ty = tid >> 4, tx = tid & 15;  // rows {ty, ty+16}, cols {tx+16j}
  float acc0[8], acc1[8];
  #pragma unroll
  for (int j = 0; j < 8; ++j) { acc0[j] = 0.f; acc1[j] = 0.f; }
  float npart = 0.f;                       // query-norm partial for (ni, ns8)
  const int ni = tid >> 3, ns8 = tid & 7;

  for (int c0 = 0; c0 < CH; c0 += 16) {
    __syncthreads();  // protect stile/qtile from previous iteration readers
    #pragma unroll
    for (int p = 0; p < 2; ++p) {
      int idx = p * 256 + tid;             // 0..511
      int nk = idx >> 2, cq = idx & 3;
      float4 v = make_float4(0.f, 0.f, 0.f, 0.f);
      if (nk < MS) v = *(const float4*)(sbase + (size_t)nk * CH + c0 + cq * 4);
      *(float4*)&stile[nk * 20 + cq * 4] = v;  // pad 20: aligned b128, 2-way banks (free)
    }
    for (int idx = tid; idx < 400; idx += 256)
      qtile[idx] = qbase[c0 * 25 + idx];   // contiguous, coalesced
    __syncthreads();
    if (ni < HW) {                         // query inv-norm accumulation (2 rows/thread)
      float v0 = qtile[ns8 * 25 + ni], v1 = qtile[(ns8 + 8) * 25 + ni];
      npart += v0 * v0 + v1 * v1;
    }
    #pragma unroll
    for (int cc = 0; cc < 16; cc += 4) {
      float a0[4], a1[4];
      #pragma unroll
      for (int u = 0; u < 4; ++u) {
        a0[u] = qtile[(cc + u) * 25 + ty];
        a1[u] = (ty < 9) ? qtile[(cc + u) * 25 + ty + 16] : 0.f;
      }
      #pragma unroll
      for (int j = 0; j < 8; ++j) {
        const float4 bv = *(const float4*)&stile[(tx + 16 * j) * 20 + cc];
        acc0[j] += a0[0] * bv.x + a0[1] * bv.y + a0[2] * bv.z + a0[3] * bv.w;
        acc1[j] += a1[0] * bv.x + a1[1] * bv.y + a1[2] * bv.z + a1[3] * bv.w;
      }
    }
  }
  {
    float p = npart;
    p += __shfl_xor(p, 1); p += __shfl_xor(p, 2); p += __shfl_xor(p, 4);
    if (ni < HW && ns8 == 0) invq[ni] = rsqrtf(p + EPS);
  }
  __syncthreads();
  {
    float iv0 = invq[ty];
    float iv1 = (ty < 9) ? invq[ty + 16] : 0.f;
    #pragma unroll
    for (int j = 0; j < 8; ++j) {
      int col = tx + 16 * j;
      if (col < MS) {
        Sld[ty * MS + col] = acc0[j] * iv0;
        if (ty < 9) Sld[(ty + 16) * MS + col] = acc1[j] * iv1;
      }
    }
  }
  __syncthreads();

  // column softmax with GAMMA2 -> Qm[j][i]  (one thread per column)
  if (tid < MS) {
    float mx = -1e30f;
    #pragma unroll
    for (int i = 0; i < HW; ++i) mx = fmaxf(mx, Sld[i * MS + tid]);
    float e[HW]; float sum = 0.f;
    #pragma unroll
    for (int i = 0; i < HW; ++i) { e[i] = __expf(GAMMA2 * (Sld[i * MS + tid] - mx)); sum += e[i]; }
    float is = 1.f / sum;
    #pragma unroll
    for (int i = 0; i < HW; ++i) Qm[tid * HW + i] = e[i] * is;
  }
  __syncthreads();

  // row softmax with GAMMA, IN-PLACE on Sld -> P  (8 threads per row)
  {
    int i = tid >> 3, s8 = tid & 7;
    if (i < HW) {
      float mx = -1e30f;
      for (int j = s8; j < MS; j += 8) mx = fmaxf(mx, Sld[i * MS + j]);
      mx = fmaxf(mx, __shfl_xor(mx, 1));
      mx = fmaxf(mx, __shfl_xor(mx, 2));
      mx = fmaxf(mx, __shfl_xor(mx, 4));
      float sum = 0.f;
      for (int j = s8; j < MS; j += 8) {
        float e = __expf(GAMMA * (Sld[i * MS + j] - mx));
        Sld[i * MS + j] = e; sum += e;
      }
      sum += __shfl_xor(sum, 1); sum += __shfl_xor(sum, 2); sum += __shfl_xor(sum, 4);
      float is = 1.f / sum;
      for (int j = s8; j < MS; j += 8) Sld[i * MS + j] *= is;
    }
  }
  __syncthreads();
  float* P = Sld;  // row-normalized in place

  // BA (+ B*1 via i2==25) into registers, then overlay Msol onto dead Qm.
  float ba[3];
  #pragma unroll
  for (int t = 0; t < 3; ++t) {
    ba[t] = 0.f;
    const int pp = tid + 256 * t;
    if (pp < 650) {
      const int i = pp / 26, i2 = pp - 26 * i;
      float s = 0.f;
      if (i2 < 25) {
        for (int j = 0; j < MS; ++j) s += Qm[j * HW + i] * P[i2 * MS + j];
      } else {
        for (int j = 0; j < MS; ++j) s += Qm[j * HW + i];
      }
      ba[t] = s;
    }
  }
  __syncthreads();
  #pragma unroll
  for (int t = 0; t < 3; ++t) {
    const int pp = tid + 256 * t;
    if (pp < 650) {
      const int i = pp / 26, i2 = pp - 26 * i;
      if (i2 < 25) Msol[i * 27 + i2] = (i == i2 ? 1.0 : 0.0) - 0.998001 * (double)ba[t];
      else         Msol[i * 27 + 25] = 1.0 + 0.999 * (double)ba[t];
    }
  }
  __syncthreads();

  // Gaussian elimination, no pivoting (column-diagonally-dominant)
  for (int k = 0; k < 24; ++k) {
    const double invp = 1.0 / Msol[k * 27 + k];
    int jj = k + 1 + (tid & 31);
    for (int i = k + 1 + (tid >> 5); i < HW; i += 8) {
      const double f = Msol[i * 27 + k] * invp;
      if (jj <= HW) Msol[i * 27 + jj] -= f * Msol[k * 27 + jj];
    }
    __syncthreads();
  }
  // back substitution
  for (int k = 24; k >= 0; --k) {
    const double xk = Msol[k * 27 + 25] / Msol[k * 27 + k];
    if (tid == 0) xsd[k] = xk;
    if (tid < k) Msol[tid * 27 + 25] -= Msol[tid * 27 + k] * xk;
    __syncthreads();
  }

  // outputs: kq = x_q - 1 (normalized); ks = c * P^T x_q (per-n normalized)
  if (tid < HW) kqs[tid] = (float)(xsd[tid] - 1.0);
  if (tid < MS) {
    float a = 0.f;
    #pragma unroll
    for (int i = 0; i < HW; ++i) a += P[i * MS + tid] * (float)xsd[i];
    ksf[tid] = 0.999f * a;
  }
  __syncthreads();
  if (tid < HW) {
    float s = 0.f;
    #pragma unroll
    for (int i = 0; i < HW; ++i) s += kqs[i];
    out[(size_t)bq * HW + tid] = kqs[tid] / s;
  }
  if (tid < MS) {
    int n = tid / HW;
    float s = 0.f;
    #pragma unroll
    for (int k2 = 0; k2 < HW; ++k2) s += ksf[n * HW + k2];
    out[60000 + (size_t)bq * MS + tid] = ksf[tid] / s;
  }
}

extern "C" void kernel_launch(void* const* d_in, const int* in_sizes, int n_in,
                              void* d_out, int out_size, void* d_ws, size_t ws_size,
                              hipStream_t stream) {
  const float* sup = (const float*)d_in[0];
  const float* qry = (const float*)d_in[1];
  float* outp = (float*)d_out;
  float* sup_t = (float*)d_ws;             // 32*125*640*4 = 10.24 MB (proven fit)
  prep_sup_kernel<<<160, 256, 0, stream>>>(sup, sup_t);
  melmask_kernel<<<2400, 256, 0, stream>>>(qry, sup_t, outp);
}

// Round 8
// 550.685 us; speedup vs baseline: 4.0760x; 4.0760x over previous
//
#include <hip/hip_runtime.h>

namespace {
constexpr int CH = 640, HW = 25, MS = 125;
constexpr int CHW = CH * HW;    // 16000
constexpr float GAMMA = 20.f, GAMMA2 = 10.f;
constexpr float EPS = 1e-12f;
}

// Shot-mean + L2-normalize (over c) + transpose to sup_t[b][nk][c]. (round-1 verbatim)
__global__ __launch_bounds__(256)
void prep_sup_kernel(const float* __restrict__ sup, float* __restrict__ sup_t) {
  __shared__ __align__(16) float m[CHW];   // mean tile [c][k]
  __shared__ float inv[HW];
  const int bn = blockIdx.x;               // b*5 + n
  const float* base = sup + (size_t)(bn / 5) * (25 * CHW)
                          + (size_t)(bn % 5) * (5 * CHW);
  for (int idx = threadIdx.x; idx < CHW; idx += 256) {
    float s = 0.f;
    #pragma unroll
    for (int sh = 0; sh < 5; ++sh) s += base[sh * CHW + idx];
    m[idx] = s * 0.2f;
  }
  __syncthreads();
  {
    int i = threadIdx.x >> 3, s8 = threadIdx.x & 7;
    if (i < HW) {
      float p = 0.f;
      for (int c = s8; c < CH; c += 8) { float v = m[c * HW + i]; p += v * v; }
      p += __shfl_xor(p, 1); p += __shfl_xor(p, 2); p += __shfl_xor(p, 4);
      if (s8 == 0) inv[i] = rsqrtf(p + EPS);
    }
  }
  __syncthreads();
  float* outp = sup_t + (size_t)bn * CHW;  // [nk][c], coalesced writes
  for (int idx = threadIdx.x; idx < CHW; idx += 256) {
    int k = idx / CH, c = idx - k * CH;
    outp[idx] = m[c * HW + k] * inv[k];
  }
}

// Per-(b,q): chunked-A GEMM -> softmaxes -> reduced 25x25 f64 Katz solve -> outputs.
__global__ __launch_bounds__(256)
void melmask_kernel(const float* __restrict__ qry, const float* __restrict__ sup_t,
                    float* __restrict__ out) {
  __shared__ __align__(16) float smem[9224];
  // [0,3125)     Sld = S[i][nk] (stride 125); later in-place P
  // [3136,5696)  stile 128x20 sup chunk; later ksf[125] overlay
  // [5696,6096)  qtile 16x25 query chunk
  // [6096,9221)  Qm[j][i] (stride 25); later overlaid by Msol (675 f64)
  float* Sld   = smem;
  float* stile = smem + 3136;
  float* qtile = smem + 5696;
  float* Qm    = smem + 6096;
  double* Msol = (double*)(smem + 6096);   // 6096*4 % 8 == 0
  float* ksf   = smem + 3136;
  __shared__ double xsd[HW];
  __shared__ float invq[HW];
  __shared__ float kqs[HW];

  const int tid = threadIdx.x;
  const int bq = blockIdx.x;               // b*75 + q
  const int b = bq / 75;
  const float* qbase = qry + (size_t)bq * CHW;
  const float* sbase = sup_t + (size_t)b * (MS * CH);

  // GEMM: S[i][nk] = sum_c q[c*25+i] * sup_t[nk*640+c]   (25 x 125, K=640)
  const int ty = tid >> 4, tx = tid & 15;  // rows {ty, ty+16}, cols {tx+16j}
  float acc0[8], acc1[8];
  #pragma unroll
  for (int j = 0; j < 8; ++j) { acc0[j] = 0.f; acc1[j] = 0.f; }
  float npart = 0.f;                       // query-norm partial for (ni, ns8)
  const int ni = tid >> 3, ns8 = tid & 7;

  for (int c0 = 0; c0 < CH; c0 += 16) {
    __syncthreads();  // protect stile/qtile from previous iteration readers
    #pragma unroll
    for (int p = 0; p < 2; ++p) {
      int idx = p * 256 + tid;             // 0..511
      int nk = idx >> 2, cq = idx & 3;
      float4 v = make_float4(0.f, 0.f, 0.f, 0.f);
      if (nk < MS) v = *(const float4*)(sbase + (size_t)nk * CH + c0 + cq * 4);
      *(float4*)&stile[nk * 20 + cq * 4] = v;  // pad 20: aligned b128, 2-way banks (free)
    }
    for (int idx = tid; idx < 400; idx += 256)
      qtile[idx] = qbase[c0 * 25 + idx];   // contiguous, coalesced
    __syncthreads();
    if (ni < HW) {                         // query inv-norm accumulation (2 rows/thread)
      float v0 = qtile[ns8 * 25 + ni], v1 = qtile[(ns8 + 8) * 25 + ni];
      npart += v0 * v0 + v1 * v1;
    }
    #pragma unroll
    for (int cc = 0; cc < 16; cc += 4) {
      float a0[4], a1[4];
      #pragma unroll
      for (int u = 0; u < 4; ++u) {
        a0[u] = qtile[(cc + u) * 25 + ty];
        a1[u] = (ty < 9) ? qtile[(cc + u) * 25 + ty + 16] : 0.f;
      }
      #pragma unroll
      for (int j = 0; j < 8; ++j) {
        const float4 bv = *(const float4*)&stile[(tx + 16 * j) * 20 + cc];
        acc0[j] += a0[0] * bv.x + a0[1] * bv.y + a0[2] * bv.z + a0[3] * bv.w;
        acc1[j] += a1[0] * bv.x + a1[1] * bv.y + a1[2] * bv.z + a1[3] * bv.w;
      }
    }
  }
  {
    float p = npart;
    p += __shfl_xor(p, 1); p += __shfl_xor(p, 2); p += __shfl_xor(p, 4);
    if (ni < HW && ns8 == 0) invq[ni] = rsqrtf(p + EPS);
  }
  __syncthreads();
  {
    float iv0 = invq[ty];
    float iv1 = (ty < 9) ? invq[ty + 16] : 0.f;
    #pragma unroll
    for (int j = 0; j < 8; ++j) {
      int col = tx + 16 * j;
      if (col < MS) {
        Sld[ty * MS + col] = acc0[j] * iv0;
        if (ty < 9) Sld[(ty + 16) * MS + col] = acc1[j] * iv1;
      }
    }
  }
  __syncthreads();

  // column softmax with GAMMA2 -> Qm[j][i]  (one thread per column)
  if (tid < MS) {
    float mx = -1e30f;
    #pragma unroll
    for (int i = 0; i < HW; ++i) mx = fmaxf(mx, Sld[i * MS + tid]);
    float e[HW]; float sum = 0.f;
    #pragma unroll
    for (int i = 0; i < HW; ++i) { e[i] = __expf(GAMMA2 * (Sld[i * MS + tid] - mx)); sum += e[i]; }
    float is = 1.f / sum;
    #pragma unroll
    for (int i = 0; i < HW; ++i) Qm[tid * HW + i] = e[i] * is;
  }
  __syncthreads();

  // row softmax with GAMMA, IN-PLACE on Sld -> P  (8 threads per row)
  {
    int i = tid >> 3, s8 = tid & 7;
    if (i < HW) {
      float mx = -1e30f;
      for (int j = s8; j < MS; j += 8) mx = fmaxf(mx, Sld[i * MS + j]);
      mx = fmaxf(mx, __shfl_xor(mx, 1));
      mx = fmaxf(mx, __shfl_xor(mx, 2));
      mx = fmaxf(mx, __shfl_xor(mx, 4));
      float sum = 0.f;
      for (int j = s8; j < MS; j += 8) {
        float e = __expf(GAMMA * (Sld[i * MS + j] - mx));
        Sld[i * MS + j] = e; sum += e;
      }
      sum += __shfl_xor(sum, 1); sum += __shfl_xor(sum, 2); sum += __shfl_xor(sum, 4);
      float is = 1.f / sum;
      for (int j = s8; j < MS; j += 8) Sld[i * MS + j] *= is;
    }
  }
  __syncthreads();
  float* P = Sld;  // row-normalized in place

  // BA (+ B*1 via i2==25) into registers, then overlay Msol onto dead Qm.
  float ba[3];
  #pragma unroll
  for (int t = 0; t < 3; ++t) {
    ba[t] = 0.f;
    const int pp = tid + 256 * t;
    if (pp < 650) {
      const int i = pp / 26, i2 = pp - 26 * i;
      float s = 0.f;
      if (i2 < 25) {
        for (int j = 0; j < MS; ++j) s += Qm[j * HW + i] * P[i2 * MS + j];
      } else {
        for (int j = 0; j < MS; ++j) s += Qm[j * HW + i];
      }
      ba[t] = s;
    }
  }
  __syncthreads();
  #pragma unroll
  for (int t = 0; t < 3; ++t) {
    const int pp = tid + 256 * t;
    if (pp < 650) {
      const int i = pp / 26, i2 = pp - 26 * i;
      if (i2 < 25) Msol[i * 27 + i2] = (i == i2 ? 1.0 : 0.0) - 0.998001 * (double)ba[t];
      else         Msol[i * 27 + 25] = 1.0 + 0.999 * (double)ba[t];
    }
  }
  __syncthreads();

  // Gaussian elimination, no pivoting (column-diagonally-dominant)
  for (int k = 0; k < 24; ++k) {
    const double invp = 1.0 / Msol[k * 27 + k];
    int jj = k + 1 + (tid & 31);
    for (int i = k + 1 + (tid >> 5); i < HW; i += 8) {
      const double f = Msol[i * 27 + k] * invp;
      if (jj <= HW) Msol[i * 27 + jj] -= f * Msol[k * 27 + jj];
    }
    __syncthreads();
  }
  // back substitution
  for (int k = 24; k >= 0; --k) {
    const double xk = Msol[k * 27 + 25] / Msol[k * 27 + k];
    if (tid == 0) xsd[k] = xk;
    if (tid < k) Msol[tid * 27 + 25] -= Msol[tid * 27 + k] * xk;
    __syncthreads();
  }

  // outputs: kq = x_q - 1 (normalized); ks = c * P^T x_q (per-n normalized)
  if (tid < HW) kqs[tid] = (float)(xsd[tid] - 1.0);
  if (tid < MS) {
    float a = 0.f;
    #pragma unroll
    for (int i = 0; i < HW; ++i) a += P[i * MS + tid] * (float)xsd[i];
    ksf[tid] = 0.999f * a;
  }
  __syncthreads();
  if (tid < HW) {
    float s = 0.f;
    #pragma unroll
    for (int i = 0; i < HW; ++i) s += kqs[i];
    out[(size_t)bq * HW + tid] = kqs[tid] / s;
  }
  if (tid < MS) {
    int n = tid / HW;
    float s = 0.f;
    #pragma unroll
    for (int k2 = 0; k2 < HW; ++k2) s += ksf[n * HW + k2];
    out[60000 + (size_t)bq * MS + tid] = ksf[tid] / s;
  }
}

extern "C" void kernel_launch(void* const* d_in, const int* in_sizes, int n_in,
                              void* d_out, int out_size, void* d_ws, size_t ws_size,
                              hipStream_t stream) {
  const float* sup = (const float*)d_in[0];
  const float* qry = (const float*)d_in[1];
  float* outp = (float*)d_out;
  float* sup_t = (float*)d_ws;             // 32*125*640*4 = 10.24 MB (proven fit)
  prep_sup_kernel<<<160, 256, 0, stream>>>(sup, sup_t);
  melmask_kernel<<<2400, 256, 0, stream>>>(qry, sup_t, outp);
}

// Round 9
// 306.712 us; speedup vs baseline: 7.3183x; 1.7954x over previous
//
#include <hip/hip_runtime.h>

namespace {
constexpr int CH = 640, HW = 25, MS = 125;
constexpr int CHW = CH * HW;    // 16000
constexpr float GAMMA = 20.f, GAMMA2 = 10.f;
constexpr float EPS = 1e-12f;
}

// Shot-mean + L2-normalize (over c) + transpose to sup_t[b][nk][c]. (proven)
__global__ __launch_bounds__(256)
void prep_sup_kernel(const float* __restrict__ sup, float* __restrict__ sup_t) {
  __shared__ __align__(16) float m[CHW];   // mean tile [c][k]
  __shared__ float inv[HW];
  const int bn = blockIdx.x;               // b*5 + n
  const float* base = sup + (size_t)(bn / 5) * (25 * CHW)
                          + (size_t)(bn % 5) * (5 * CHW);
  for (int idx = threadIdx.x; idx < CHW; idx += 256) {
    float s = 0.f;
    #pragma unroll
    for (int sh = 0; sh < 5; ++sh) s += base[sh * CHW + idx];
    m[idx] = s * 0.2f;
  }
  __syncthreads();
  {
    int i = threadIdx.x >> 3, s8 = threadIdx.x & 7;
    if (i < HW) {
      float p = 0.f;
      for (int c = s8; c < CH; c += 8) { float v = m[c * HW + i]; p += v * v; }
      p += __shfl_xor(p, 1); p += __shfl_xor(p, 2); p += __shfl_xor(p, 4);
      if (s8 == 0) inv[i] = rsqrtf(p + EPS);
    }
  }
  __syncthreads();
  float* outp = sup_t + (size_t)bn * CHW;  // [nk][c], coalesced writes
  for (int idx = threadIdx.x; idx < CHW; idx += 256) {
    int k = idx / CH, c = idx - k * CH;
    outp[idx] = m[c * HW + k] * inv[k];
  }
}

// One block per (b, 5-query group): 125x125 S GEMM (8x8 reg tiles) ->
// per-query softmaxes -> BA -> reduced 25x25 f64 Katz solve -> outputs.
__global__ __launch_bounds__(256)
void melmask_kernel(const float* __restrict__ qry, const float* __restrict__ sup_t,
                    float* __restrict__ out) {
  __shared__ __align__(16) float pool[4224]; // atile[16][132] | btile[16][132]; Qm overlay
  __shared__ __align__(16) float Sld[3125];  // per-query S[r][col] stride 125; in-place P
  __shared__ double Msol[675];               // augmented 25x26, stride 27
  __shared__ double xsd[HW];
  __shared__ float invq_s[128];
  __shared__ float kqs[HW];
  __shared__ float ksf[MS];

  float* atile = pool;
  float* btile = pool + 2112;
  float* Qm    = pool;                       // overlays staging after GEMM

  const int tid = threadIdx.x;
  // XCD swizzle: 480 = 8*60; same-XCD blocks share 4 consecutive b's (B panel 1.28MB/L2).
  const int Bl = (blockIdx.x & 7) * 60 + (blockIdx.x >> 3);
  const int b = Bl / 15, qg = Bl - 15 * b;
  const float* qbase = qry + ((size_t)b * 75 + (size_t)qg * 5) * CHW;
  const float* sbase = sup_t + (size_t)b * (MS * CH);
  const int ty = tid >> 4, tx = tid & 15;    // rows {4ty+u, 64+4ty+u}, cols {4tx+v, 64+4tx+v}

  float acc[2][2][4][4];
  #pragma unroll
  for (int g = 0; g < 2; ++g)
    #pragma unroll
    for (int h = 0; h < 2; ++h)
      #pragma unroll
      for (int u = 0; u < 4; ++u)
        #pragma unroll
        for (int v = 0; v < 4; ++v) acc[g][h][u][v] = 0.f;
  float npart = 0.f;

  for (int c0 = 0; c0 < CH; c0 += 16) {
    __syncthreads();                         // protect staging from prev readers
    #pragma unroll
    for (int mm = 0; mm < 8; ++mm) {         // A: 16k x 128row
      int idx = tid + 256 * mm;
      int k = idx >> 7, row = idx & 127;
      float v = 0.f;
      if (row < MS) {
        int qq = row / 25, i = row - 25 * qq;
        v = qbase[(size_t)qq * CHW + (size_t)(c0 + k) * 25 + i];
      }
      atile[k * 132 + row] = v;
    }
    #pragma unroll
    for (int mm = 0; mm < 2; ++mm) {         // B: 16k x 128col (transpose via float4)
      int idx = tid + 256 * mm;
      int col = idx >> 2, kq = idx & 3;
      float4 v = make_float4(0.f, 0.f, 0.f, 0.f);
      if (col < MS) v = *(const float4*)(sbase + (size_t)col * CH + c0 + 4 * kq);
      btile[(4 * kq + 0) * 132 + col] = v.x;
      btile[(4 * kq + 1) * 132 + col] = v.y;
      btile[(4 * kq + 2) * 132 + col] = v.z;
      btile[(4 * kq + 3) * 132 + col] = v.w;
    }
    __syncthreads();
    if (tid < MS) {                          // query inv-norm accumulation
      #pragma unroll
      for (int k = 0; k < 16; ++k) { float v = atile[k * 132 + tid]; npart += v * v; }
    }
    #pragma unroll
    for (int k = 0; k < 16; ++k) {
      const float4 a0 = *(const float4*)&atile[k * 132 + 4 * ty];
      const float4 a1 = *(const float4*)&atile[k * 132 + 64 + 4 * ty];
      const float4 b0 = *(const float4*)&btile[k * 132 + 4 * tx];
      const float4 b1 = *(const float4*)&btile[k * 132 + 64 + 4 * tx];
      const float ag[2][4] = {{a0.x, a0.y, a0.z, a0.w}, {a1.x, a1.y, a1.z, a1.w}};
      const float bg[2][4] = {{b0.x, b0.y, b0.z, b0.w}, {b1.x, b1.y, b1.z, b1.w}};
      #pragma unroll
      for (int g = 0; g < 2; ++g)
        #pragma unroll
        for (int u = 0; u < 4; ++u)
          #pragma unroll
          for (int h = 0; h < 2; ++h)
            #pragma unroll
            for (int v = 0; v < 4; ++v) acc[g][h][u][v] += ag[g][u] * bg[h][v];
    }
  }
  if (tid < MS) invq_s[tid] = rsqrtf(npart + EPS);
  __syncthreads();

  for (int qq = 0; qq < 5; ++qq) {
    const int bq = b * 75 + qg * 5 + qq;
    const int r0 = qq * 25;
    // ---- scatter this query's S rows (normalized) into Sld ----
    #pragma unroll
    for (int g = 0; g < 2; ++g)
      #pragma unroll
      for (int u = 0; u < 4; ++u) {
        const int row = g * 64 + 4 * ty + u;
        if (row >= r0 && row < r0 + 25) {
          const int r = row - r0;
          const float iv = invq_s[row];
          #pragma unroll
          for (int h = 0; h < 2; ++h)
            #pragma unroll
            for (int v = 0; v < 4; ++v) {
              const int col = h * 64 + 4 * tx + v;
              if (col < MS) Sld[r * MS + col] = acc[g][h][u][v] * iv;
            }
        }
      }
    __syncthreads();

    // ---- column softmax with GAMMA2 -> Qm[col][i] ----
    if (tid < MS) {
      float mx = -1e30f;
      #pragma unroll
      for (int i = 0; i < HW; ++i) mx = fmaxf(mx, Sld[i * MS + tid]);
      float e[HW]; float sum = 0.f;
      #pragma unroll
      for (int i = 0; i < HW; ++i) { e[i] = __expf(GAMMA2 * (Sld[i * MS + tid] - mx)); sum += e[i]; }
      float is = 1.f / sum;
      #pragma unroll
      for (int i = 0; i < HW; ++i) Qm[tid * HW + i] = e[i] * is;
    }
    __syncthreads();

    // ---- row softmax with GAMMA, in place -> P ----
    {
      int i = tid >> 3, s8 = tid & 7;
      if (i < HW) {
        float mx = -1e30f;
        for (int j = s8; j < MS; j += 8) mx = fmaxf(mx, Sld[i * MS + j]);
        mx = fmaxf(mx, __shfl_xor(mx, 1));
        mx = fmaxf(mx, __shfl_xor(mx, 2));
        mx = fmaxf(mx, __shfl_xor(mx, 4));
        float sum = 0.f;
        for (int j = s8; j < MS; j += 8) {
          float e = __expf(GAMMA * (Sld[i * MS + j] - mx));
          Sld[i * MS + j] = e; sum += e;
        }
        sum += __shfl_xor(sum, 1); sum += __shfl_xor(sum, 2); sum += __shfl_xor(sum, 4);
        float is = 1.f / sum;
        for (int j = s8; j < MS; j += 8) Sld[i * MS + j] *= is;
      }
    }
    __syncthreads();
    float* P = Sld;

    // ---- BA (+ B*1 via i2==25) into registers ----
    float ba[3];
    #pragma unroll
    for (int t = 0; t < 3; ++t) {
      ba[t] = 0.f;
      const int pp = tid + 256 * t;
      if (pp < 650) {
        const int i = pp / 26, i2 = pp - 26 * i;
        float s = 0.f;
        if (i2 < 25) {
          for (int j = 0; j < MS; ++j) s += Qm[j * HW + i] * P[i2 * MS + j];
        } else {
          for (int j = 0; j < MS; ++j) s += Qm[j * HW + i];
        }
        ba[t] = s;
      }
    }
    __syncthreads();
    #pragma unroll
    for (int t = 0; t < 3; ++t) {
      const int pp = tid + 256 * t;
      if (pp < 650) {
        const int i = pp / 26, i2 = pp - 26 * i;
        if (i2 < 25) Msol[i * 27 + i2] = (i == i2 ? 1.0 : 0.0) - 0.998001 * (double)ba[t];
        else         Msol[i * 27 + 25] = 1.0 + 0.999 * (double)ba[t];
      }
    }
    __syncthreads();

    // ---- Gaussian elimination, no pivoting (column-diagonally-dominant) ----
    for (int k = 0; k < 24; ++k) {
      const double invp = 1.0 / Msol[k * 27 + k];
      int jj = k + 1 + (tid & 31);
      for (int i = k + 1 + (tid >> 5); i < HW; i += 8) {
        const double f = Msol[i * 27 + k] * invp;
        if (jj <= HW) Msol[i * 27 + jj] -= f * Msol[k * 27 + jj];
      }
      __syncthreads();
    }
    for (int k = 24; k >= 0; --k) {
      const double xk = Msol[k * 27 + 25] / Msol[k * 27 + k];
      if (tid == 0) xsd[k] = xk;
      if (tid < k) Msol[tid * 27 + 25] -= Msol[tid * 27 + k] * xk;
      __syncthreads();
    }

    // ---- outputs ----
    if (tid < HW) kqs[tid] = (float)(xsd[tid] - 1.0);
    if (tid < MS) {
      float a = 0.f;
      #pragma unroll
      for (int i = 0; i < HW; ++i) a += P[i * MS + tid] * (float)xsd[i];
      ksf[tid] = 0.999f * a;
    }
    __syncthreads();
    if (tid < HW) {
      float s = 0.f;
      #pragma unroll
      for (int i = 0; i < HW; ++i) s += kqs[i];
      out[(size_t)bq * HW + tid] = kqs[tid] / s;
    }
    if (tid < MS) {
      int n = tid / HW;
      float s = 0.f;
      #pragma unroll
      for (int k2 = 0; k2 < HW; ++k2) s += ksf[n * HW + k2];
      out[60000 + (size_t)bq * MS + tid] = ksf[tid] / s;
    }
    __syncthreads();   // Sld/Qm/Msol reuse fence for next query
  }
}

extern "C" void kernel_launch(void* const* d_in, const int* in_sizes, int n_in,
                              void* d_out, int out_size, void* d_ws, size_t ws_size,
                              hipStream_t stream) {
  const float* sup = (const float*)d_in[0];
  const float* qry = (const float*)d_in[1];
  float* outp = (float*)d_out;
  float* sup_t = (float*)d_ws;             // 32*125*640*4 = 10.24 MB (proven fit)
  prep_sup_kernel<<<160, 256, 0, stream>>>(sup, sup_t);
  melmask_kernel<<<480, 256, 0, stream>>>(qry, sup_t, outp);
}